// Round 16
// baseline (246.077 us; speedup 1.0000x reference)
//
#include <hip/hip_runtime.h>
#include <hip/hip_bf16.h>
#include <stdint.h>

// ---------------------------------------------------------------------------
// TernaryExpert via INT8 MFMA (R16 = R13 numerics, occupancy-first GEMM):
// 128x128 tile, 256 thr (4 waves, 64x64/wave), acc=64 VGPR (~110 total,
// NO launch_bounds min-waves -> no R14 spill trap), double-buffered 32KB LDS
// -> ~4 blocks/CU co-resident. Desynced blocks overlap MFMA vs read/stage
// (m114 mechanism). Per tile: 8 ds_read + 4 gload_lds + 16 MFMA + vmcnt(0)
// + 1 barrier. Same 0-conflict swizzle (chunk ^= (row>>1)&3, both sides).
// Numerics identical to R13/R15 (absmax 5.0).
// ---------------------------------------------------------------------------

#define M_ROWS   16384
#define D_MODEL  1024
#define D_FF     4096
#define NW       (D_FF * D_MODEL)

typedef __attribute__((ext_vector_type(4))) int   i32x4;
typedef __attribute__((ext_vector_type(4))) float f32x4;

__device__ __forceinline__ void gload_lds16(const void* g, void* l) {
    __builtin_amdgcn_global_load_lds(
        (const __attribute__((address_space(1))) void*)g,
        (__attribute__((address_space(3))) void*)l, 16, 0, 0);
}

#define BAR()     __builtin_amdgcn_s_barrier()
#define VMCNT(n)  asm volatile("s_waitcnt vmcnt(" #n ")" ::: "memory")

__device__ __forceinline__ float gelu_fast(float v) {
    float w = v * v;
    float z = v * __builtin_fmaf(w, 0.07135481627f, 1.5957691216f);
    float e = __expf(-z);
    return v / (1.0f + e);
}
__device__ __forceinline__ int q8(float v) {
    int q = __float2int_rn(v);
    return (q > 127) ? 127 : ((q < -127) ? -127 : q);
}

// ---------------------------------------------------------------------------
// aux kernels (identical numerics to R13/R15)
// ---------------------------------------------------------------------------
__global__ __launch_bounds__(256) void absmean_reduce(const float* __restrict__ w,
                                                      double* __restrict__ asum) {
    const int n4 = NW / 4;
    float s = 0.f;
    const float4* w4 = (const float4*)w;
    for (int i = blockIdx.x * blockDim.x + threadIdx.x; i < n4;
         i += gridDim.x * blockDim.x) {
        float4 v = w4[i];
        s += fabsf(v.x) + fabsf(v.y) + fabsf(v.z) + fabsf(v.w);
    }
    #pragma unroll
    for (int off = 32; off > 0; off >>= 1) s += __shfl_down(s, off);
    __shared__ float sm[4];
    int lane = threadIdx.x & 63, wid = threadIdx.x >> 6;
    if (lane == 0) sm[wid] = s;
    __syncthreads();
    if (threadIdx.x == 0) {
        float t = sm[0] + sm[1] + sm[2] + sm[3];
        atomicAdd(asum, (double)t);
    }
}

__global__ __launch_bounds__(256) void quant_w8(const float* __restrict__ w,
                                                const double* __restrict__ asum,
                                                char* __restrict__ wq) {
    float thr = (float)(0.5 * (*asum) * (1.0 / (double)NW));
    int i = blockIdx.x * blockDim.x + threadIdx.x;
    float4 v = ((const float4*)w)[i];
    int b0 = (fabsf(v.x) > thr) ? (v.x > 0.f ? 1 : -1) : 0;
    int b1 = (fabsf(v.y) > thr) ? (v.y > 0.f ? 1 : -1) : 0;
    int b2 = (fabsf(v.z) > thr) ? (v.z > 0.f ? 1 : -1) : 0;
    int b3 = (fabsf(v.w) > thr) ? (v.w > 0.f ? 1 : -1) : 0;
    ((int*)wq)[i] = (b0 & 0xff) | ((b1 & 0xff) << 8) |
                    ((b2 & 0xff) << 16) | ((b3 & 0xff) << 24);
}

__global__ __launch_bounds__(256) void rmsnorm_xq(const float* __restrict__ x,
                                                  char* __restrict__ xq) {
    const int row = blockIdx.x;
    const float4* xr = (const float4*)(x + (size_t)row * D_MODEL);
    float4 v = xr[threadIdx.x];
    float ss = v.x * v.x + v.y * v.y + v.z * v.z + v.w * v.w;
    #pragma unroll
    for (int off = 32; off > 0; off >>= 1) ss += __shfl_down(ss, off);
    __shared__ float sm[4];
    int lane = threadIdx.x & 63, wid = threadIdx.x >> 6;
    if (lane == 0) sm[wid] = ss;
    __syncthreads();
    float tot = sm[0] + sm[1] + sm[2] + sm[3];
    float s = 24.0f / (sqrtf(tot) * (1.0f / 32.0f) + 1e-8f);
    int b0 = q8(v.x * s), b1 = q8(v.y * s), b2 = q8(v.z * s), b3 = q8(v.w * s);
    ((int*)(xq + (size_t)row * D_MODEL))[threadIdx.x] =
        (b0 & 0xff) | ((b1 & 0xff) << 8) | ((b2 & 0xff) << 16) | ((b3 & 0xff) << 24);
}

__global__ __launch_bounds__(256) void rowscale_hq(const char* __restrict__ hq,
                                                   float* __restrict__ rs) {
    const int row = blockIdx.x;
    const int4* hr = (const int4*)(hq + (size_t)row * D_FF);
    int4 d = hr[threadIdx.x];
    float ss = 0.f;
    #pragma unroll
    for (int w = 0; w < 4; ++w) {
        int dw = (w == 0) ? d.x : (w == 1) ? d.y : (w == 2) ? d.z : d.w;
        #pragma unroll
        for (int b = 0; b < 4; ++b) {
            int q = (int)(char)((dw >> (8 * b)) & 0xff);
            ss += (float)(q * q);
        }
    }
    #pragma unroll
    for (int off = 32; off > 0; off >>= 1) ss += __shfl_down(ss, off);
    __shared__ float sm[4];
    int lane = threadIdx.x & 63, wid = threadIdx.x >> 6;
    if (lane == 0) sm[wid] = ss;
    __syncthreads();
    if (threadIdx.x == 0) {
        float tot = sm[0] + sm[1] + sm[2] + sm[3];
        rs[row] = 1.0f / (sqrtf(tot) * (1.0f / 64.0f) + 1e-8f);
    }
}

// ---------------------------------------------------------------------------
// i8 GEMM: C[m][n] = sum_k A[m,k]*B[n,k], A/B i8 K-contig.
// 128x128 tile, BK=64. LDS buffer (16KB): A 128x64B @0, B 128x64B @8192.
// 2 buffers (32KB). 4 waves: wm=wid>>1 (64-row slice), wn=wid&1 (64-col).
// Staging: slot s = tid + inst*256 -> row = s>>2, ch = s&3,
//          src col = (ch ^ ((row>>1)&3))*16; dst = region + s*16.
// Per tile: 8 ds_read + {2 A + 2 B gload_lds} + 16 MFMA + vmcnt(0) + BAR.
// ---------------------------------------------------------------------------
template <int EPI, int KDIM, int NBLKN>
__global__ __launch_bounds__(256) void gemm_i8o(const char* __restrict__ A,
                                                const char* __restrict__ B,
                                                char* __restrict__ Cq,
                                                float* __restrict__ Cf,
                                                const float* __restrict__ rowscale,
                                                int nwg) {
    constexpr int BUFB = 16384;
    constexpr int NT = KDIM / 64;
    __shared__ char smem[2 * BUFB];

    const int tid = threadIdx.x;
    const int bid = blockIdx.x;
    const int swz = (bid & 7) * (nwg >> 3) + (bid >> 3);
    const uint m0 = (uint)(swz / NBLKN) * 128u;
    const uint n0 = (uint)(swz % NBLKN) * 128u;

    const int lane = tid & 63;
    const int wid  = tid >> 6;
    const int wm   = wid >> 1;                  // 0..1 -> 64-row slice
    const int wn   = wid & 1;                   // 0..1 -> 64-col slice
    const int lr   = lane & 15;
    const int lk   = lane >> 4;                 // 16B k-chunk 0..3

    // staging source (inverse swizzle), per inst in {0,1}
    uint aOff[2], bOff[2];
    #pragma unroll
    for (int inst = 0; inst < 2; ++inst) {
        uint s = (uint)tid + (uint)inst * 256u;
        uint row = s >> 2, ch = s & 3u;
        uint src = ((ch ^ ((row >> 1) & 3u)) << 4);
        aOff[inst] = (m0 + row) * (uint)KDIM + src;
        bOff[inst] = (n0 + row) * (uint)KDIM + src;
    }
    const uint dstOff = (uint)tid * 16u;

    // fragment read offsets (bytes)
    uint offA[4], offB[4];
    #pragma unroll
    for (int i = 0; i < 4; ++i) {
        uint rowa = (uint)(wm * 64 + i * 16 + lr);
        offA[i] = rowa * 64u + (((uint)lk ^ ((rowa >> 1) & 3u)) << 4);
        uint rowb = (uint)(wn * 64 + i * 16 + lr);
        offB[i] = 8192u + rowb * 64u + (((uint)lk ^ ((rowb >> 1) & 3u)) << 4);
    }

    i32x4 acc[4][4];
    #pragma unroll
    for (int mi = 0; mi < 4; ++mi)
        #pragma unroll
        for (int ni = 0; ni < 4; ++ni)
            acc[mi][ni] = (i32x4){0, 0, 0, 0};

    // prologue: stage tile 0 into buf 0
    {
        gload_lds16(A + aOff[0], smem +        0 + dstOff);
        gload_lds16(A + aOff[1], smem +     4096 + dstOff);
        gload_lds16(B + bOff[0], smem +     8192 + dstOff);
        gload_lds16(B + bOff[1], smem +    12288 + dstOff);
    }
    VMCNT(0);
    BAR();

    #pragma unroll 1
    for (int t = 0; t < NT; ++t) {
        const char* cb = smem + (t & 1) * BUFB;
        char* sb = smem + ((t + 1) & 1) * BUFB;
        const uint kc = (uint)(t + 1) * 64u;
        const bool doS = (t + 1 < NT);
        i32x4 av[4], bv[4];

        #pragma unroll
        for (int i = 0; i < 4; ++i) av[i] = *(const i32x4*)(cb + offA[i]);
        #pragma unroll
        for (int i = 0; i < 4; ++i) bv[i] = *(const i32x4*)(cb + offB[i]);
        if (doS) {
            gload_lds16(A + aOff[0] + kc, sb +     0 + dstOff);
            gload_lds16(A + aOff[1] + kc, sb +  4096 + dstOff);
            gload_lds16(B + bOff[0] + kc, sb +  8192 + dstOff);
            gload_lds16(B + bOff[1] + kc, sb + 12288 + dstOff);
        }
        __builtin_amdgcn_s_setprio(1);
        #pragma unroll
        for (int mi = 0; mi < 4; ++mi)
            #pragma unroll
            for (int ni = 0; ni < 4; ++ni)
                acc[mi][ni] = __builtin_amdgcn_mfma_i32_16x16x64_i8(
                    av[mi], bv[ni], acc[mi][ni], 0, 0, 0);
        __builtin_amdgcn_s_setprio(0);

        if (doS) { VMCNT(0); }     // tile t+1 fully landed
        BAR();
    }

    // epilogue: C/D frag mapping col = lane&15, row = (lane>>4)*4 + reg
    constexpr uint N = (uint)NBLKN * 128u;
    #pragma unroll
    for (int mi = 0; mi < 4; ++mi) {
        #pragma unroll
        for (int j = 0; j < 4; ++j) {
            const uint gr = m0 + (uint)(wm * 64 + mi * 16 + lk * 4 + j);
            float s = 0.f;
            if (EPI == 1) s = rowscale[gr];
            #pragma unroll
            for (int ni = 0; ni < 4; ++ni) {
                const uint gc = n0 + (uint)(wn * 64 + ni * 16 + lr);
                if (EPI == 0) {
                    float g = gelu_fast((float)acc[mi][ni][j] * (1.0f / 24.0f));
                    Cq[gr * N + gc] = (char)q8(g);
                } else {
                    Cf[gr * N + gc] = (float)acc[mi][ni][j] * s;
                }
            }
        }
    }
}

// ---------------------------------------------------------------------------
extern "C" void kernel_launch(void* const* d_in, const int* in_sizes, int n_in,
                              void* d_out, int out_size, void* d_ws, size_t ws_size,
                              hipStream_t stream) {
    const float* x    = (const float*)d_in[0];
    const float* w_up = (const float*)d_in[1];
    const float* w_dn = (const float*)d_in[2];
    float* out = (float*)d_out;

    uint8_t* ws = (uint8_t*)d_ws;
    char* hq  = (char*)(ws);                                   // 64 MB
    char* xq  = (char*)(ws + 67108864);                        // 16 MB
    char* wqu = (char*)(ws + 67108864 + 16777216);             // 4 MB
    char* wqd = (char*)(ws + 67108864 + 16777216 + 4194304);   // 4 MB
    float*  rs   = (float*)(ws + 67108864 + 16777216 + 2 * 4194304);
    double* alph = (double*)(ws + 67108864 + 16777216 + 2 * 4194304 + 65536);

    hipMemsetAsync(alph, 0, 16, stream);

    absmean_reduce<<<256, 256, 0, stream>>>(w_up, alph + 0);
    absmean_reduce<<<256, 256, 0, stream>>>(w_dn, alph + 1);
    quant_w8<<<NW / 1024, 256, 0, stream>>>(w_up, alph + 0, wqu);
    quant_w8<<<NW / 1024, 256, 0, stream>>>(w_dn, alph + 1, wqd);
    rmsnorm_xq<<<M_ROWS, 256, 0, stream>>>(x, xq);

    // L1: hq = q8(gelu((xq @ wqu^T)/24))  [16384 x 4096], K=1024
    // grid 128 x 32 = 4096 blocks
    gemm_i8o<0, D_MODEL, 32><<<4096, 256, 0, stream>>>(
        xq, wqu, hq, nullptr, nullptr, 4096);

    rowscale_hq<<<M_ROWS, 256, 0, stream>>>(hq, rs);

    // L2: out = (hq @ wqd^T) * rs[m]  [16384 x 1024], K=4096
    // grid 128 x 8 = 1024 blocks
    gemm_i8o<1, D_FF, 8><<<1024, 256, 0, stream>>>(
        hq, wqd, nullptr, out, rs, 1024);
}

// Round 17
// 222.775 us; speedup vs baseline: 1.1046x; 1.1046x over previous
//
#include <hip/hip_runtime.h>
#include <hip/hip_bf16.h>
#include <stdint.h>

// ---------------------------------------------------------------------------
// TernaryExpert via INT8 MFMA (R17: byte-minimal multi-block geometry):
// Model from R8/R12/R13/R15/R16: per-CU global-return BW caps at ~16 B/cy
// (multi-block configs saturate it; single-block configs are request-limited
// at 8-12). So: minimize logical bytes SUBJECT TO >=2 co-resident blocks.
// 256x128 tile, BK=64, 512 thr (8 waves 4Mx2N, 64x64/wave), acc=64 VGPR
// (~75 total, no launch_bounds min-waves), double-buffered 48KB LDS
// -> 2-3 blocks/CU. Logical bytes L1 = 768MB (vs 1GB R16 / 512MB-1blk R13).
// Loop = R16's proven single phase: 8 ds_read + 3 gload_lds + 16 MFMA +
// vmcnt(0) + 1 barrier per K-tile. Same 0-conflict swizzle, same numerics
// as R13/R15/R16 (absmax exactly 5.0).
// ---------------------------------------------------------------------------

#define M_ROWS   16384
#define D_MODEL  1024
#define D_FF     4096
#define NW       (D_FF * D_MODEL)

typedef __attribute__((ext_vector_type(4))) int   i32x4;
typedef __attribute__((ext_vector_type(4))) float f32x4;

__device__ __forceinline__ void gload_lds16(const void* g, void* l) {
    __builtin_amdgcn_global_load_lds(
        (const __attribute__((address_space(1))) void*)g,
        (__attribute__((address_space(3))) void*)l, 16, 0, 0);
}

#define BAR()     __builtin_amdgcn_s_barrier()
#define VMCNT(n)  asm volatile("s_waitcnt vmcnt(" #n ")" ::: "memory")

__device__ __forceinline__ float gelu_fast(float v) {
    float w = v * v;
    float z = v * __builtin_fmaf(w, 0.07135481627f, 1.5957691216f);
    float e = __expf(-z);
    return v / (1.0f + e);
}
__device__ __forceinline__ int q8(float v) {
    int q = __float2int_rn(v);
    return (q > 127) ? 127 : ((q < -127) ? -127 : q);
}

// ---------------------------------------------------------------------------
// aux kernels (identical numerics to R13/R15/R16)
// ---------------------------------------------------------------------------
__global__ __launch_bounds__(256) void absmean_reduce(const float* __restrict__ w,
                                                      double* __restrict__ asum) {
    const int n4 = NW / 4;
    float s = 0.f;
    const float4* w4 = (const float4*)w;
    for (int i = blockIdx.x * blockDim.x + threadIdx.x; i < n4;
         i += gridDim.x * blockDim.x) {
        float4 v = w4[i];
        s += fabsf(v.x) + fabsf(v.y) + fabsf(v.z) + fabsf(v.w);
    }
    #pragma unroll
    for (int off = 32; off > 0; off >>= 1) s += __shfl_down(s, off);
    __shared__ float sm[4];
    int lane = threadIdx.x & 63, wid = threadIdx.x >> 6;
    if (lane == 0) sm[wid] = s;
    __syncthreads();
    if (threadIdx.x == 0) {
        float t = sm[0] + sm[1] + sm[2] + sm[3];
        atomicAdd(asum, (double)t);
    }
}

__global__ __launch_bounds__(256) void quant_w8(const float* __restrict__ w,
                                                const double* __restrict__ asum,
                                                char* __restrict__ wq) {
    float thr = (float)(0.5 * (*asum) * (1.0 / (double)NW));
    int i = blockIdx.x * blockDim.x + threadIdx.x;
    float4 v = ((const float4*)w)[i];
    int b0 = (fabsf(v.x) > thr) ? (v.x > 0.f ? 1 : -1) : 0;
    int b1 = (fabsf(v.y) > thr) ? (v.y > 0.f ? 1 : -1) : 0;
    int b2 = (fabsf(v.z) > thr) ? (v.z > 0.f ? 1 : -1) : 0;
    int b3 = (fabsf(v.w) > thr) ? (v.w > 0.f ? 1 : -1) : 0;
    ((int*)wq)[i] = (b0 & 0xff) | ((b1 & 0xff) << 8) |
                    ((b2 & 0xff) << 16) | ((b3 & 0xff) << 24);
}

__global__ __launch_bounds__(256) void rmsnorm_xq(const float* __restrict__ x,
                                                  char* __restrict__ xq) {
    const int row = blockIdx.x;
    const float4* xr = (const float4*)(x + (size_t)row * D_MODEL);
    float4 v = xr[threadIdx.x];
    float ss = v.x * v.x + v.y * v.y + v.z * v.z + v.w * v.w;
    #pragma unroll
    for (int off = 32; off > 0; off >>= 1) ss += __shfl_down(ss, off);
    __shared__ float sm[4];
    int lane = threadIdx.x & 63, wid = threadIdx.x >> 6;
    if (lane == 0) sm[wid] = ss;
    __syncthreads();
    float tot = sm[0] + sm[1] + sm[2] + sm[3];
    float s = 24.0f / (sqrtf(tot) * (1.0f / 32.0f) + 1e-8f);
    int b0 = q8(v.x * s), b1 = q8(v.y * s), b2 = q8(v.z * s), b3 = q8(v.w * s);
    ((int*)(xq + (size_t)row * D_MODEL))[threadIdx.x] =
        (b0 & 0xff) | ((b1 & 0xff) << 8) | ((b2 & 0xff) << 16) | ((b3 & 0xff) << 24);
}

__global__ __launch_bounds__(256) void rowscale_hq(const char* __restrict__ hq,
                                                   float* __restrict__ rs) {
    const int row = blockIdx.x;
    const int4* hr = (const int4*)(hq + (size_t)row * D_FF);
    int4 d = hr[threadIdx.x];
    float ss = 0.f;
    #pragma unroll
    for (int w = 0; w < 4; ++w) {
        int dw = (w == 0) ? d.x : (w == 1) ? d.y : (w == 2) ? d.z : d.w;
        #pragma unroll
        for (int b = 0; b < 4; ++b) {
            int q = (int)(char)((dw >> (8 * b)) & 0xff);
            ss += (float)(q * q);
        }
    }
    #pragma unroll
    for (int off = 32; off > 0; off >>= 1) ss += __shfl_down(ss, off);
    __shared__ float sm[4];
    int lane = threadIdx.x & 63, wid = threadIdx.x >> 6;
    if (lane == 0) sm[wid] = ss;
    __syncthreads();
    if (threadIdx.x == 0) {
        float tot = sm[0] + sm[1] + sm[2] + sm[3];
        rs[row] = 1.0f / (sqrtf(tot) * (1.0f / 64.0f) + 1e-8f);
    }
}

// ---------------------------------------------------------------------------
// i8 GEMM: C[m][n] = sum_k A[m,k]*B[n,k], A/B i8 K-contig.
// 256x128 tile, BK=64. LDS buffer (24KB): A 256x64B @0, B 128x64B @16384.
// 2 buffers (48KB). 8 waves: wm=wid>>1 (64-row), wn=wid&1 (64-col).
// Staging/thread: 2 A insts (1024 slots) + 1 B inst (512 slots);
// slot s -> row = s>>2, ch = s&3, src col = (ch ^ ((row>>1)&3))*16.
// Per tile: 8 ds_read + 3 gload_lds + 16 MFMA + vmcnt(0) + 1 barrier.
// ---------------------------------------------------------------------------
template <int EPI, int KDIM, int NBLKN>
__global__ __launch_bounds__(512) void gemm_i8w(const char* __restrict__ A,
                                                const char* __restrict__ B,
                                                char* __restrict__ Cq,
                                                float* __restrict__ Cf,
                                                const float* __restrict__ rowscale,
                                                int nwg) {
    constexpr int BUFB = 24576;
    constexpr int NT = KDIM / 64;
    __shared__ char smem[2 * BUFB];

    const int tid = threadIdx.x;
    const int bid = blockIdx.x;
    const int swz = (bid & 7) * (nwg >> 3) + (bid >> 3);
    const uint m0 = (uint)(swz / NBLKN) * 256u;
    const uint n0 = (uint)(swz % NBLKN) * 128u;

    const int lane = tid & 63;
    const int wid  = tid >> 6;
    const int wm   = wid >> 1;                  // 0..3 -> 64-row slice
    const int wn   = wid & 1;                   // 0..1 -> 64-col slice
    const int lr   = lane & 15;
    const int lk   = lane >> 4;                 // 16B k-chunk 0..3

    // staging source (inverse swizzle)
    uint aOff[2], bOff;
    #pragma unroll
    for (int inst = 0; inst < 2; ++inst) {
        uint s = (uint)tid + (uint)inst * 512u;
        uint row = s >> 2, ch = s & 3u;
        uint src = ((ch ^ ((row >> 1) & 3u)) << 4);
        aOff[inst] = (m0 + row) * (uint)KDIM + src;
    }
    {
        uint row = (uint)tid >> 2, ch = (uint)tid & 3u;
        uint src = ((ch ^ ((row >> 1) & 3u)) << 4);
        bOff = (n0 + row) * (uint)KDIM + src;
    }
    const uint dstOff = (uint)tid * 16u;

    // fragment read offsets (bytes)
    uint offA[4], offB[4];
    #pragma unroll
    for (int i = 0; i < 4; ++i) {
        uint rowa = (uint)(wm * 64 + i * 16 + lr);
        offA[i] = rowa * 64u + (((uint)lk ^ ((rowa >> 1) & 3u)) << 4);
        uint rowb = (uint)(wn * 64 + i * 16 + lr);
        offB[i] = 16384u + rowb * 64u + (((uint)lk ^ ((rowb >> 1) & 3u)) << 4);
    }

    i32x4 acc[4][4];
    #pragma unroll
    for (int mi = 0; mi < 4; ++mi)
        #pragma unroll
        for (int ni = 0; ni < 4; ++ni)
            acc[mi][ni] = (i32x4){0, 0, 0, 0};

    // prologue: stage tile 0 into buf 0
    {
        gload_lds16(A + aOff[0], smem +     0 + dstOff);
        gload_lds16(A + aOff[1], smem +  8192 + dstOff);
        gload_lds16(B + bOff,    smem + 16384 + dstOff);
    }
    VMCNT(0);
    BAR();

    #pragma unroll 1
    for (int t = 0; t < NT; ++t) {
        const char* cb = smem + (t & 1) * BUFB;
        char* sb = smem + ((t + 1) & 1) * BUFB;
        const uint kc = (uint)(t + 1) * 64u;
        const bool doS = (t + 1 < NT);
        i32x4 av[4], bv[4];

        #pragma unroll
        for (int i = 0; i < 4; ++i) av[i] = *(const i32x4*)(cb + offA[i]);
        #pragma unroll
        for (int i = 0; i < 4; ++i) bv[i] = *(const i32x4*)(cb + offB[i]);
        if (doS) {
            gload_lds16(A + aOff[0] + kc, sb +     0 + dstOff);
            gload_lds16(A + aOff[1] + kc, sb +  8192 + dstOff);
            gload_lds16(B + bOff    + kc, sb + 16384 + dstOff);
        }
        __builtin_amdgcn_s_setprio(1);
        #pragma unroll
        for (int mi = 0; mi < 4; ++mi)
            #pragma unroll
            for (int ni = 0; ni < 4; ++ni)
                acc[mi][ni] = __builtin_amdgcn_mfma_i32_16x16x64_i8(
                    av[mi], bv[ni], acc[mi][ni], 0, 0, 0);
        __builtin_amdgcn_s_setprio(0);

        if (doS) { VMCNT(0); }     // tile t+1 fully landed
        BAR();
    }

    // epilogue: C/D frag mapping col = lane&15, row = (lane>>4)*4 + reg
    constexpr uint N = (uint)NBLKN * 128u;
    #pragma unroll
    for (int mi = 0; mi < 4; ++mi) {
        #pragma unroll
        for (int j = 0; j < 4; ++j) {
            const uint gr = m0 + (uint)(wm * 64 + mi * 16 + lk * 4 + j);
            float s = 0.f;
            if (EPI == 1) s = rowscale[gr];
            #pragma unroll
            for (int ni = 0; ni < 4; ++ni) {
                const uint gc = n0 + (uint)(wn * 64 + ni * 16 + lr);
                if (EPI == 0) {
                    float g = gelu_fast((float)acc[mi][ni][j] * (1.0f / 24.0f));
                    Cq[gr * N + gc] = (char)q8(g);
                } else {
                    Cf[gr * N + gc] = (float)acc[mi][ni][j] * s;
                }
            }
        }
    }
}

// ---------------------------------------------------------------------------
extern "C" void kernel_launch(void* const* d_in, const int* in_sizes, int n_in,
                              void* d_out, int out_size, void* d_ws, size_t ws_size,
                              hipStream_t stream) {
    const float* x    = (const float*)d_in[0];
    const float* w_up = (const float*)d_in[1];
    const float* w_dn = (const float*)d_in[2];
    float* out = (float*)d_out;

    uint8_t* ws = (uint8_t*)d_ws;
    char* hq  = (char*)(ws);                                   // 64 MB
    char* xq  = (char*)(ws + 67108864);                        // 16 MB
    char* wqu = (char*)(ws + 67108864 + 16777216);             // 4 MB
    char* wqd = (char*)(ws + 67108864 + 16777216 + 4194304);   // 4 MB
    float*  rs   = (float*)(ws + 67108864 + 16777216 + 2 * 4194304);
    double* alph = (double*)(ws + 67108864 + 16777216 + 2 * 4194304 + 65536);

    hipMemsetAsync(alph, 0, 16, stream);

    absmean_reduce<<<256, 256, 0, stream>>>(w_up, alph + 0);
    absmean_reduce<<<256, 256, 0, stream>>>(w_dn, alph + 1);
    quant_w8<<<NW / 1024, 256, 0, stream>>>(w_up, alph + 0, wqu);
    quant_w8<<<NW / 1024, 256, 0, stream>>>(w_dn, alph + 1, wqd);
    rmsnorm_xq<<<M_ROWS, 256, 0, stream>>>(x, xq);

    // L1: hq = q8(gelu((xq @ wqu^T)/24))  [16384 x 4096], K=1024
    // grid 64 x 32 = 2048 blocks
    gemm_i8w<0, D_MODEL, 32><<<2048, 512, 0, stream>>>(
        xq, wqu, hq, nullptr, nullptr, 2048);

    rowscale_hq<<<M_ROWS, 256, 0, stream>>>(hq, rs);

    // L2: out = (hq @ wqd^T) * rs[m]  [16384 x 1024], K=4096
    // grid 64 x 8 = 512 blocks
    gemm_i8w<1, D_FF, 8><<<512, 512, 0, stream>>>(
        hq, wqd, nullptr, out, rs, 512);
}